// Round 4
// baseline (279.819 us; speedup 1.0000x reference)
//
#include <hip/hip_runtime.h>
#include <hip/hip_fp16.h>

#define N_NODES 50000
#define N_EDGES 800000
#define F_INN   128
#define F_HID   96
#define F_OUTT  40

// ---------------------------------------------------------------------------
// CSR build: count(+rank) -> 3-phase parallel scan (+dinv) -> atomic-free fill
// ---------------------------------------------------------------------------

// counts[dst]++ ; rank[i] = this edge's slot within its dst row (atomic return).
__global__ void count_kernel(const int* __restrict__ dst, int* __restrict__ counts,
                             int* __restrict__ rank, int e) {
    int i = blockIdx.x * blockDim.x + threadIdx.x;
    if (i < e) rank[i] = atomicAdd(&counts[dst[i]], 1);
}

// Phase 1: per-block (1024-wide) exclusive scan; write local scan + dinv + block sum.
__global__ __launch_bounds__(1024) void scan_local_kernel(
        const int* __restrict__ counts, int* __restrict__ row_start,
        float* __restrict__ dinv, int* __restrict__ blk_sums, int n) {
    __shared__ int wave_sums[16];
    int tid = threadIdx.x, lane = tid & 63, wid = tid >> 6;
    int i = blockIdx.x * 1024 + tid;
    int v = (i < n) ? counts[i] : 0;
    int val = v;
    #pragma unroll
    for (int off = 1; off < 64; off <<= 1) {
        int u = __shfl_up(val, off, 64);
        if (lane >= off) val += u;
    }
    if (lane == 63) wave_sums[wid] = val;
    __syncthreads();
    if (wid == 0) {
        int w = (lane < 16) ? wave_sums[lane] : 0;
        #pragma unroll
        for (int off = 1; off < 16; off <<= 1) {
            int u = __shfl_up(w, off, 64);
            if (lane >= off) w += u;
        }
        if (lane < 16) wave_sums[lane] = w;   // inclusive wave totals
    }
    __syncthreads();
    int excl = ((wid == 0) ? 0 : wave_sums[wid - 1]) + (val - v);
    if (i < n) {
        row_start[i] = excl;                  // local (no global offset yet)
        dinv[i] = rsqrtf((float)(v + 1));     // +1 self loop
    }
    if (tid == 0) blk_sums[blockIdx.x] = wave_sums[15];
}

// Phase 2: one wave scans <=64 block sums -> exclusive offsets; writes total.
__global__ void scan_blk_kernel(const int* __restrict__ blk_sums, int* __restrict__ blk_off,
                                int* __restrict__ row_start, int n, int nblk) {
    int lane = threadIdx.x;
    int v = (lane < nblk) ? blk_sums[lane] : 0;
    int val = v;
    #pragma unroll
    for (int off = 1; off < 64; off <<= 1) {
        int u = __shfl_up(val, off, 64);
        if (lane >= off) val += u;
    }
    if (lane < nblk) blk_off[lane] = val - v;
    if (lane == 63) row_start[n] = val;       // == E
}

// Phase 3: add block offset.
__global__ __launch_bounds__(1024) void scan_apply_kernel(
        int* __restrict__ row_start, const int* __restrict__ blk_off, int n) {
    int i = blockIdx.x * 1024 + threadIdx.x;
    if (i < n) row_start[i] += blk_off[blockIdx.x];
}

// Atomic-free fill: pos = row_start[dst] + rank.  One scattered 4B store.
__global__ void fill_csr_kernel(const int* __restrict__ src, const int* __restrict__ dst,
                                const int* __restrict__ rank, const int* __restrict__ row_start,
                                int* __restrict__ csr_src, int e) {
    int i = blockIdx.x * blockDim.x + threadIdx.x;
    if (i >= e) return;
    csr_src[row_start[dst[i]] + rank[i]] = src[i];
}

// ---------------------------------------------------------------------------
// GEMM: T'[n][96] = dinv[n] * (A[n x FI] @ W[FI x 96]), stored fp16.
// blockDim (24,16): thread = 4 j x 4 nodes (strided 16). W in LDS.
// ---------------------------------------------------------------------------

template <int FI>
__global__ __launch_bounds__(384) void gemm96_kernel(
        const float* __restrict__ A, const float* __restrict__ W,
        const float* __restrict__ dinv, __half2* __restrict__ C, int n) {
    __shared__ float Wlds[FI * 96];
    int tid = threadIdx.y * 24 + threadIdx.x;
    for (int i = tid; i < FI * 24; i += 384)
        reinterpret_cast<float4*>(Wlds)[i] = reinterpret_cast<const float4*>(W)[i];
    __syncthreads();

    int j  = threadIdx.x * 4;                 // 0..92
    int n0 = blockIdx.x * 64 + threadIdx.y;   // nodes n0, +16, +32, +48
    int nn[4];
    #pragma unroll
    for (int t = 0; t < 4; ++t) nn[t] = min(n0 + 16 * t, n - 1);

    float4 acc[4];
    #pragma unroll
    for (int t = 0; t < 4; ++t) acc[t] = make_float4(0.f, 0.f, 0.f, 0.f);

    for (int k = 0; k < FI; k += 4) {
        float4 a[4];
        #pragma unroll
        for (int t = 0; t < 4; ++t)
            a[t] = *reinterpret_cast<const float4*>(A + (size_t)nn[t] * FI + k);
        float4 w0 = *reinterpret_cast<const float4*>(Wlds + (k + 0) * 96 + j);
        float4 w1 = *reinterpret_cast<const float4*>(Wlds + (k + 1) * 96 + j);
        float4 w2 = *reinterpret_cast<const float4*>(Wlds + (k + 2) * 96 + j);
        float4 w3 = *reinterpret_cast<const float4*>(Wlds + (k + 3) * 96 + j);
        #pragma unroll
        for (int t = 0; t < 4; ++t) {
            acc[t].x += a[t].x * w0.x + a[t].y * w1.x + a[t].z * w2.x + a[t].w * w3.x;
            acc[t].y += a[t].x * w0.y + a[t].y * w1.y + a[t].z * w2.y + a[t].w * w3.y;
            acc[t].z += a[t].x * w0.z + a[t].y * w1.z + a[t].z * w2.z + a[t].w * w3.z;
            acc[t].w += a[t].x * w0.w + a[t].y * w1.w + a[t].z * w2.w + a[t].w * w3.w;
        }
    }
    #pragma unroll
    for (int t = 0; t < 4; ++t) {
        int node = n0 + 16 * t;
        if (node < n) {
            float dn = dinv[node];
            __half2 h01 = __floats2half2_rn(acc[t].x * dn, acc[t].y * dn);
            __half2 h23 = __floats2half2_rn(acc[t].z * dn, acc[t].w * dn);
            __half2* Cp = C + (size_t)node * 48 + (j >> 1);
            Cp[0] = h01;
            Cp[1] = h23;
        }
    }
}

// Output GEMM: out[n x 40] = A[n x 96] @ W[96 x 40] + bias. blockDim (10,32).
__global__ __launch_bounds__(320) void gemm_out_kernel(
        const float* __restrict__ A, const float* __restrict__ W,
        const float* __restrict__ bias, float* __restrict__ C, int n) {
    __shared__ float Wlds[96 * 40];
    int tid = threadIdx.y * 10 + threadIdx.x;
    for (int i = tid; i < 96 * 10; i += 320)
        reinterpret_cast<float4*>(Wlds)[i] = reinterpret_cast<const float4*>(W)[i];
    __syncthreads();

    int j    = threadIdx.x * 4;               // 0..36
    int node = blockIdx.x * 32 + threadIdx.y;
    int nc   = min(node, n - 1);
    float4 acc = make_float4(0.f, 0.f, 0.f, 0.f);
    for (int k = 0; k < 96; k += 4) {
        float4 a = *reinterpret_cast<const float4*>(A + (size_t)nc * 96 + k);
        float4 w0 = *reinterpret_cast<const float4*>(Wlds + (k + 0) * 40 + j);
        float4 w1 = *reinterpret_cast<const float4*>(Wlds + (k + 1) * 40 + j);
        float4 w2 = *reinterpret_cast<const float4*>(Wlds + (k + 2) * 40 + j);
        float4 w3 = *reinterpret_cast<const float4*>(Wlds + (k + 3) * 40 + j);
        acc.x += a.x * w0.x + a.y * w1.x + a.z * w2.x + a.w * w3.x;
        acc.y += a.x * w0.y + a.y * w1.y + a.z * w2.y + a.w * w3.y;
        acc.z += a.x * w0.z + a.y * w1.z + a.z * w2.z + a.w * w3.z;
        acc.w += a.x * w0.w + a.y * w1.w + a.z * w2.w + a.w * w3.w;
    }
    if (node < n) {
        float4 b = *reinterpret_cast<const float4*>(bias + j);
        acc.x += b.x; acc.y += b.y; acc.z += b.z; acc.w += b.w;
        *reinterpret_cast<float4*>(C + (size_t)node * 40 + j) = acc;
    }
}

// ---------------------------------------------------------------------------
// Aggregation v3: one WAVE per node, FIVE edges per wave-instruction.
// Row = 96 halves = 192B = 12 lanes x float4. Lane l: e = l/12 (edge slot
// 0..4; e==5 idle), f = l%12 (16B chunk). Per iteration the wave gathers
// 5 edges' rows in ONE load instruction; csr indices are software-pipelined.
// Epilogue: shuffle-reduce the 5 slices, lanes 0..11 write the row.
//   H[d] = relu( dinv[d] * (T'[d] + sum_e T'[src_e]) + b )
// ---------------------------------------------------------------------------

__device__ inline void acc8(float* acc, float4 r) {
    const __half2* h = reinterpret_cast<const __half2*>(&r);
    #pragma unroll
    for (int i = 0; i < 4; ++i) {
        float2 f2 = __half22float2(h[i]);
        acc[2 * i]     += f2.x;
        acc[2 * i + 1] += f2.y;
    }
}

__global__ __launch_bounds__(256) void agg_kernel(
        const float4* __restrict__ T4,       // fp16 rows: 12 float4 per node
        const int* __restrict__ row_start,
        const int* __restrict__ csr_src,
        const float* __restrict__ dinv,
        const float* __restrict__ bias,
        float4* __restrict__ H4, int n) {   // fp32 rows: 24 float4 per node
    int lane = threadIdx.x & 63;
    int node = __builtin_amdgcn_readfirstlane(blockIdx.x * 4 + (threadIdx.x >> 6));
    if (node >= n) return;
    int e = lane / 12;            // 0..5
    int f = lane - e * 12;        // 0..11
    bool lact = (e < 5);

    float acc[8];
    #pragma unroll
    for (int i = 0; i < 8; ++i) acc[i] = 0.f;

    // self loop: slice e==0 accumulates the node's own row
    if (e == 0) acc8(acc, T4[(size_t)node * 12 + f]);

    int beg = row_start[node];
    int end = row_start[node + 1];

    // software-pipelined 5-wide edge loop
    int p = beg + e;
    bool v = lact && (p < end);
    int s = v ? csr_src[p] : node;
    for (int idx = beg; idx < end; idx += 5) {
        int  pn = p + 5;
        bool vn = lact && (pn < end);
        int  sn = vn ? csr_src[pn] : node;
        float4 r = T4[(size_t)s * 12 + f];   // 5 rows per wave instruction
        if (v) acc8(acc, r);
        p = pn; v = vn; s = sn;
    }

    // reduce the 5 slices: lane (e=0,f) sums lanes f, f+12, f+24, f+36, f+48
    float tot[8];
    #pragma unroll
    for (int i = 0; i < 8; ++i) tot[i] = acc[i];
    #pragma unroll
    for (int k = 1; k < 5; ++k) {
        #pragma unroll
        for (int i = 0; i < 8; ++i)
            tot[i] += __shfl(acc[i], f + 12 * k, 64);   // reads unmodified acc
    }

    if (e == 0) {                 // lanes 0..11 write features 8f..8f+7
        float dn = dinv[node];
        const float4* b4 = reinterpret_cast<const float4*>(bias);
        float4 b0 = b4[2 * f], b1 = b4[2 * f + 1];
        float4 o0, o1;
        o0.x = fmaxf(dn * tot[0] + b0.x, 0.f);
        o0.y = fmaxf(dn * tot[1] + b0.y, 0.f);
        o0.z = fmaxf(dn * tot[2] + b0.z, 0.f);
        o0.w = fmaxf(dn * tot[3] + b0.w, 0.f);
        o1.x = fmaxf(dn * tot[4] + b1.x, 0.f);
        o1.y = fmaxf(dn * tot[5] + b1.y, 0.f);
        o1.z = fmaxf(dn * tot[6] + b1.z, 0.f);
        o1.w = fmaxf(dn * tot[7] + b1.w, 0.f);
        H4[(size_t)node * 24 + 2 * f]     = o0;
        H4[(size_t)node * 24 + 2 * f + 1] = o1;
    }
}

// ---------------------------------------------------------------------------

extern "C" void kernel_launch(void* const* d_in, const int* in_sizes, int n_in,
                              void* d_out, int out_size, void* d_ws, size_t ws_size,
                              hipStream_t stream) {
    const float* x    = (const float*)d_in[0];
    const int*   ei   = (const int*)d_in[1];
    const float* W1   = (const float*)d_in[2];
    const float* b1   = (const float*)d_in[3];
    const float* W2   = (const float*)d_in[4];
    const float* b2   = (const float*)d_in[5];
    const float* Wout = (const float*)d_in[6];
    const float* bout = (const float*)d_in[7];
    float*       out  = (float*)d_out;

    const int* src = ei;            // edge_index[0]
    const int* dst = ei + N_EDGES;  // edge_index[1]

    char* ws = (char*)d_ws;
    size_t off = 0;
    auto alloc = [&](size_t bytes) {
        size_t o = off;
        off = (off + bytes + 511) & ~(size_t)511;
        return (void*)(ws + o);
    };
    int*     counts    = (int*)    alloc(N_NODES * sizeof(int));
    int*     row_start = (int*)    alloc((N_NODES + 1) * sizeof(int));
    float*   dinv      = (float*)  alloc(N_NODES * sizeof(float));
    int*     blk_sums  = (int*)    alloc(64 * sizeof(int));
    int*     blk_off   = (int*)    alloc(64 * sizeof(int));
    int*     rank      = (int*)    alloc((size_t)N_EDGES * sizeof(int));
    int*     csr_src   = (int*)    alloc((size_t)N_EDGES * sizeof(int));
    __half2* Th        = (__half2*)alloc((size_t)N_NODES * 48 * sizeof(__half2));
    float*   Hf        = (float*)  alloc((size_t)N_NODES * F_HID * sizeof(float));

    const int NSCAN = (N_NODES + 1023) / 1024;   // 49 (<=64 for 1-wave phase 2)

    // --- CSR build (topology only, reused by both layers) ---
    hipMemsetAsync(counts, 0, N_NODES * sizeof(int), stream);
    count_kernel<<<(N_EDGES + 255) / 256, 256, 0, stream>>>(dst, counts, rank, N_EDGES);
    scan_local_kernel<<<NSCAN, 1024, 0, stream>>>(counts, row_start, dinv, blk_sums, N_NODES);
    scan_blk_kernel<<<1, 64, 0, stream>>>(blk_sums, blk_off, row_start, N_NODES, NSCAN);
    scan_apply_kernel<<<NSCAN, 1024, 0, stream>>>(row_start, blk_off, N_NODES);
    fill_csr_kernel<<<(N_EDGES + 255) / 256, 256, 0, stream>>>(
        src, dst, rank, row_start, csr_src, N_EDGES);

    // --- Layer 1: T' = dinv * (x @ W1); H = relu(dinv * (T'self + sum T'src) + b1) ---
    gemm96_kernel<F_INN><<<(N_NODES + 63) / 64, dim3(24, 16), 0, stream>>>(
        x, W1, dinv, Th, N_NODES);
    agg_kernel<<<(N_NODES + 3) / 4, 256, 0, stream>>>(
        (const float4*)Th, row_start, csr_src, dinv, b1, (float4*)Hf, N_NODES);

    // --- Layer 2 ---
    gemm96_kernel<F_HID><<<(N_NODES + 63) / 64, dim3(24, 16), 0, stream>>>(
        Hf, W2, dinv, Th, N_NODES);
    agg_kernel<<<(N_NODES + 3) / 4, 256, 0, stream>>>(
        (const float4*)Th, row_start, csr_src, dinv, b2, (float4*)Hf, N_NODES);

    // --- Output ---
    gemm_out_kernel<<<(N_NODES + 31) / 32, dim3(10, 32), 0, stream>>>(
        Hf, Wout, bout, out, N_NODES);
}

// Round 5
// 232.585 us; speedup vs baseline: 1.2031x; 1.2031x over previous
//
#include <hip/hip_runtime.h>
#include <hip/hip_fp16.h>

#define N_NODES 50000
#define N_EDGES 800000
#define F_INN   128
#define F_HID   96
#define F_OUTT  40

typedef _Float16 half8 __attribute__((ext_vector_type(8)));
typedef float    floatx4 __attribute__((ext_vector_type(4)));

// ---------------------------------------------------------------------------
// CSR build: 4-way sharded count(+rank) -> scan(+dinv,+shard bases) -> fill
// ---------------------------------------------------------------------------

// counts4[dst*4 + shard]++ ; rank = slot within (dst,shard).
__global__ void count_kernel(const int* __restrict__ dst, int* __restrict__ counts4,
                             int* __restrict__ rank, int e) {
    int i = blockIdx.x * blockDim.x + threadIdx.x;
    if (i < e) rank[i] = atomicAdd(&counts4[dst[i] * 4 + (i & 3)], 1);
}

// Phase 1: per-block exclusive scan of total counts; dinv; block sums.
__global__ __launch_bounds__(1024) void scan_local_kernel(
        const int4* __restrict__ counts4, int* __restrict__ row_start,
        float* __restrict__ dinv, int* __restrict__ blk_sums, int n) {
    __shared__ int wave_sums[16];
    int tid = threadIdx.x, lane = tid & 63, wid = tid >> 6;
    int i = blockIdx.x * 1024 + tid;
    int v = 0;
    if (i < n) {
        int4 c = counts4[i];
        v = c.x + c.y + c.z + c.w;
    }
    int val = v;
    #pragma unroll
    for (int off = 1; off < 64; off <<= 1) {
        int u = __shfl_up(val, off, 64);
        if (lane >= off) val += u;
    }
    if (lane == 63) wave_sums[wid] = val;
    __syncthreads();
    if (wid == 0) {
        int w = (lane < 16) ? wave_sums[lane] : 0;
        #pragma unroll
        for (int off = 1; off < 16; off <<= 1) {
            int u = __shfl_up(w, off, 64);
            if (lane >= off) w += u;
        }
        if (lane < 16) wave_sums[lane] = w;
    }
    __syncthreads();
    int excl = ((wid == 0) ? 0 : wave_sums[wid - 1]) + (val - v);
    if (i < n) {
        row_start[i] = excl;                  // local; offset added in phase 3
        dinv[i] = rsqrtf((float)(v + 1));     // +1 self loop
    }
    if (tid == 0) blk_sums[blockIdx.x] = wave_sums[15];
}

// Phase 2: one wave scans <=64 block sums.
__global__ void scan_blk_kernel(const int* __restrict__ blk_sums, int* __restrict__ blk_off,
                                int* __restrict__ row_start, int n, int nblk) {
    int lane = threadIdx.x;
    int v = (lane < nblk) ? blk_sums[lane] : 0;
    int val = v;
    #pragma unroll
    for (int off = 1; off < 64; off <<= 1) {
        int u = __shfl_up(val, off, 64);
        if (lane >= off) val += u;
    }
    if (lane < nblk) blk_off[lane] = val - v;
    if (lane == 63) row_start[n] = val;       // == E
}

// Phase 3: add block offset; emit per-shard bases base4[i].
__global__ __launch_bounds__(1024) void scan_apply_kernel(
        int* __restrict__ row_start, const int* __restrict__ blk_off,
        const int4* __restrict__ counts4, int4* __restrict__ base4, int n) {
    int i = blockIdx.x * 1024 + threadIdx.x;
    if (i >= n) return;
    int4 c = counts4[i];
    int b = row_start[i] + blk_off[blockIdx.x];
    row_start[i] = b;
    base4[i] = make_int4(b, b + c.x, b + c.x + c.y, b + c.x + c.y + c.z);
}

// Atomic-free fill: pos = base4[dst].shard + rank.
__global__ void fill_csr_kernel(const int* __restrict__ src, const int* __restrict__ dst,
                                const int* __restrict__ rank, const int* __restrict__ base4,
                                int* __restrict__ csr_src, int e) {
    int i = blockIdx.x * blockDim.x + threadIdx.x;
    if (i >= e) return;
    csr_src[base4[dst[i] * 4 + (i & 3)] + rank[i]] = src[i];
}

// ---------------------------------------------------------------------------
// Weight transpose + fp16 convert: W[K x 96] -> BT[96][136] halves (pad 8).
// Covers W1 (K=128) and W2 (K=96) in one launch.
// ---------------------------------------------------------------------------
__global__ void wt_kernel(const float* __restrict__ W1, const float* __restrict__ W2,
                          __half* __restrict__ BT1, __half* __restrict__ BT2) {
    int i = blockIdx.x * 256 + threadIdx.x;
    if (i < 96 * 128) {
        int j = i / 128, k = i - j * 128;
        BT1[j * 136 + k] = __float2half(W1[k * 96 + j]);
    } else if (i < 96 * 128 + 96 * 96) {
        int t = i - 96 * 128;
        int j = t / 96, k = t - j * 96;
        BT2[j * 136 + k] = __float2half(W2[k * 96 + j]);
    }
}

// ---------------------------------------------------------------------------
// MFMA GEMM: T'[n][96] (fp16) = dinv[n] * (X[n x FI] @ W), via 16x16x32 f16.
// Operand swap: A = W-tile (m=feature), B = node rows (n=node) so D[j][node]
// gives one dinv scalar per lane. 256 threads = 4 waves x 16 nodes = 64/block.
// ---------------------------------------------------------------------------
template <int FI>
__global__ __launch_bounds__(256) void mfma_gemm_kernel(
        const float* __restrict__ X, const __half* __restrict__ BTg,
        const float* __restrict__ dinv, float4* __restrict__ Th4, int n) {
    __shared__ __half BTl[96 * 136];          // 26112 B
    __shared__ __half OUTl[4 * 16 * 104];     // 13312 B, per-wave staging
    int tid = threadIdx.x;
    {   // stage BT (1632 x 16B)
        const int4* s = reinterpret_cast<const int4*>(BTg);
        int4* d = reinterpret_cast<int4*>(BTl);
        for (int i = tid; i < 96 * 136 / 8; i += 256) d[i] = s[i];
    }
    __syncthreads();

    int lane = tid & 63, w = tid >> 6;
    int lm = lane & 15, q = lane >> 4;
    int base = blockIdx.x * 64 + w * 16;
    int node = base + lm;
    int nclamp = min(node, n - 1);
    const float* Xrow = X + (size_t)nclamp * FI;

    floatx4 cf[6];
    #pragma unroll
    for (int t = 0; t < 6; ++t) cf[t] = (floatx4){0.f, 0.f, 0.f, 0.f};

    constexpr int KS = FI / 32;
    #pragma unroll
    for (int ks = 0; ks < KS; ++ks) {
        // B-operand: this node's k-slice [32ks .. 32ks+31], lane holds k=q*8..q*8+7
        const float4* xr = reinterpret_cast<const float4*>(Xrow + 32 * ks + q * 8);
        float4 f0 = xr[0], f1 = xr[1];
        union { half8 v; __half2 h[4]; } b;
        b.h[0] = __floats2half2_rn(f0.x, f0.y);
        b.h[1] = __floats2half2_rn(f0.z, f0.w);
        b.h[2] = __floats2half2_rn(f1.x, f1.y);
        b.h[3] = __floats2half2_rn(f1.z, f1.w);
        #pragma unroll
        for (int t = 0; t < 6; ++t) {
            // A-operand: W^T[feature = t*16+lm][k = q*8.. +7]
            half8 a = *reinterpret_cast<const half8*>(
                &BTl[(t * 16 + lm) * 136 + q * 8 + 32 * ks]);
            cf[t] = __builtin_amdgcn_mfma_f32_16x16x32_f16(a, b.v, cf[t], 0, 0, 0);
        }
    }

    // Epilogue: D[row=q*4+r][col=lm] = out[feature][node]; scale by dinv[node].
    float dn = dinv[nclamp];
    __half* orow = OUTl + (w * 16 + lm) * 104;
    #pragma unroll
    for (int t = 0; t < 6; ++t) {
        union { int2 i2; __half2 h[2]; } u;
        u.h[0] = __floats2half2_rn(cf[t][0] * dn, cf[t][1] * dn);
        u.h[1] = __floats2half2_rn(cf[t][2] * dn, cf[t][3] * dn);
        *reinterpret_cast<int2*>(&orow[t * 16 + q * 4]) = u.i2;   // 4 consecutive j
    }
    // Same-wave LDS round-trip (no barrier): coalesced fp16 row store.
    #pragma unroll
    for (int R = 0; R < 3; ++R) {
        int nl = lane >> 2, c = (lane & 3) + 4 * R;
        float4 v = *reinterpret_cast<const float4*>(&OUTl[(w * 16 + nl) * 104 + c * 8]);
        int gn = base + nl;
        if (gn < n) Th4[(size_t)gn * 12 + c] = v;
    }
}

// ---------------------------------------------------------------------------
// Output GEMM: out[n x 40] = A[n x 96] @ W[96 x 40] + bias (fp32 VALU).
// ---------------------------------------------------------------------------
__global__ __launch_bounds__(320) void gemm_out_kernel(
        const float* __restrict__ A, const float* __restrict__ W,
        const float* __restrict__ bias, float* __restrict__ C, int n) {
    __shared__ float Wlds[96 * 40];
    int tid = threadIdx.y * 10 + threadIdx.x;
    for (int i = tid; i < 96 * 10; i += 320)
        reinterpret_cast<float4*>(Wlds)[i] = reinterpret_cast<const float4*>(W)[i];
    __syncthreads();

    int j    = threadIdx.x * 4;
    int node = blockIdx.x * 32 + threadIdx.y;
    int nc   = min(node, n - 1);
    float4 acc = make_float4(0.f, 0.f, 0.f, 0.f);
    for (int k = 0; k < 96; k += 4) {
        float4 a = *reinterpret_cast<const float4*>(A + (size_t)nc * 96 + k);
        float4 w0 = *reinterpret_cast<const float4*>(Wlds + (k + 0) * 40 + j);
        float4 w1 = *reinterpret_cast<const float4*>(Wlds + (k + 1) * 40 + j);
        float4 w2 = *reinterpret_cast<const float4*>(Wlds + (k + 2) * 40 + j);
        float4 w3 = *reinterpret_cast<const float4*>(Wlds + (k + 3) * 40 + j);
        acc.x += a.x * w0.x + a.y * w1.x + a.z * w2.x + a.w * w3.x;
        acc.y += a.x * w0.y + a.y * w1.y + a.z * w2.y + a.w * w3.y;
        acc.z += a.x * w0.z + a.y * w1.z + a.z * w2.z + a.w * w3.z;
        acc.w += a.x * w0.w + a.y * w1.w + a.z * w2.w + a.w * w3.w;
    }
    if (node < n) {
        float4 b = *reinterpret_cast<const float4*>(bias + j);
        acc.x += b.x; acc.y += b.y; acc.z += b.z; acc.w += b.w;
        *reinterpret_cast<float4*>(C + (size_t)node * 40 + j) = acc;
    }
}

// ---------------------------------------------------------------------------
// Aggregation (round-2 proven shape, 8-deep unroll): one wave per node.
//   H[d] = relu( dinv[d] * (T'[d] + sum_e T'[src_e]) + b )
// ---------------------------------------------------------------------------
__global__ __launch_bounds__(256) void agg_kernel(
        const __half2* __restrict__ T, const int* __restrict__ row_start,
        const int* __restrict__ csr_src, const float* __restrict__ dinv,
        const float* __restrict__ bias, float* __restrict__ H, int n) {
    int lane = threadIdx.x & 63;
    int node = __builtin_amdgcn_readfirstlane(blockIdx.x * 4 + (threadIdx.x >> 6));
    if (node >= n) return;
    int fl = min(lane, 47);                    // lanes 48..63 duplicate lane 47

    float2 self = __half22float2(T[(size_t)node * 48 + fl]);
    float accx = self.x, accy = self.y;

    int idx = row_start[node];
    int end = row_start[node + 1];
    for (; idx + 8 <= end; idx += 8) {
        int s[8];
        #pragma unroll
        for (int u = 0; u < 8; ++u) s[u] = csr_src[idx + u];
        float2 f[8];
        #pragma unroll
        for (int u = 0; u < 8; ++u) f[u] = __half22float2(T[(size_t)s[u] * 48 + fl]);
        #pragma unroll
        for (int u = 0; u < 8; ++u) { accx += f[u].x; accy += f[u].y; }
    }
    for (; idx < end; ++idx) {
        float2 f = __half22float2(T[(size_t)csr_src[idx] * 48 + fl]);
        accx += f.x; accy += f.y;
    }
    if (lane < 48) {
        float dn = dinv[node];
        float2 b = reinterpret_cast<const float2*>(bias)[lane];
        float2 o;
        o.x = fmaxf(dn * accx + b.x, 0.f);
        o.y = fmaxf(dn * accy + b.y, 0.f);
        reinterpret_cast<float2*>(H)[(size_t)node * 48 + lane] = o;
    }
}

// ---------------------------------------------------------------------------

extern "C" void kernel_launch(void* const* d_in, const int* in_sizes, int n_in,
                              void* d_out, int out_size, void* d_ws, size_t ws_size,
                              hipStream_t stream) {
    const float* x    = (const float*)d_in[0];
    const int*   ei   = (const int*)d_in[1];
    const float* W1   = (const float*)d_in[2];
    const float* b1   = (const float*)d_in[3];
    const float* W2   = (const float*)d_in[4];
    const float* b2   = (const float*)d_in[5];
    const float* Wout = (const float*)d_in[6];
    const float* bout = (const float*)d_in[7];
    float*       out  = (float*)d_out;

    const int* src = ei;            // edge_index[0]
    const int* dst = ei + N_EDGES;  // edge_index[1]

    char* ws = (char*)d_ws;
    size_t off = 0;
    auto alloc = [&](size_t bytes) {
        size_t o = off;
        off = (off + bytes + 511) & ~(size_t)511;
        return (void*)(ws + o);
    };
    int*     counts4   = (int*)    alloc((size_t)N_NODES * 4 * sizeof(int));
    int4*    base4     = (int4*)   alloc((size_t)N_NODES * sizeof(int4));
    int*     row_start = (int*)    alloc((N_NODES + 1) * sizeof(int));
    float*   dinv      = (float*)  alloc(N_NODES * sizeof(float));
    int*     blk_sums  = (int*)    alloc(64 * sizeof(int));
    int*     blk_off   = (int*)    alloc(64 * sizeof(int));
    int*     rank      = (int*)    alloc((size_t)N_EDGES * sizeof(int));
    int*     csr_src   = (int*)    alloc((size_t)N_EDGES * sizeof(int));
    __half*  BT1       = (__half*) alloc((size_t)96 * 136 * sizeof(__half));
    __half*  BT2       = (__half*) alloc((size_t)96 * 136 * sizeof(__half));
    __half2* Th        = (__half2*)alloc((size_t)N_NODES * 48 * sizeof(__half2));
    float*   Hf        = (float*)  alloc((size_t)N_NODES * F_HID * sizeof(float));

    const int NSCAN = (N_NODES + 1023) / 1024;   // 49

    // --- weights prep (independent of CSR chain) ---
    wt_kernel<<<(96 * 128 + 96 * 96 + 255) / 256, 256, 0, stream>>>(W1, W2, BT1, BT2);

    // --- CSR build ---
    hipMemsetAsync(counts4, 0, (size_t)N_NODES * 4 * sizeof(int), stream);
    count_kernel<<<(N_EDGES + 255) / 256, 256, 0, stream>>>(dst, counts4, rank, N_EDGES);
    scan_local_kernel<<<NSCAN, 1024, 0, stream>>>(
        (const int4*)counts4, row_start, dinv, blk_sums, N_NODES);
    scan_blk_kernel<<<1, 64, 0, stream>>>(blk_sums, blk_off, row_start, N_NODES, NSCAN);
    scan_apply_kernel<<<NSCAN, 1024, 0, stream>>>(
        row_start, blk_off, (const int4*)counts4, base4, N_NODES);
    fill_csr_kernel<<<(N_EDGES + 255) / 256, 256, 0, stream>>>(
        src, dst, rank, (const int*)base4, csr_src, N_EDGES);

    // --- Layer 1: T' = dinv*(x@W1) via MFMA; H = relu(dinv*(self+sum)+b1) ---
    mfma_gemm_kernel<F_INN><<<(N_NODES + 63) / 64, 256, 0, stream>>>(
        x, BT1, dinv, (float4*)Th, N_NODES);
    agg_kernel<<<(N_NODES + 3) / 4, 256, 0, stream>>>(
        Th, row_start, csr_src, dinv, b1, Hf, N_NODES);

    // --- Layer 2 ---
    mfma_gemm_kernel<F_HID><<<(N_NODES + 63) / 64, 256, 0, stream>>>(
        Hf, BT2, dinv, (float4*)Th, N_NODES);
    agg_kernel<<<(N_NODES + 3) / 4, 256, 0, stream>>>(
        Th, row_start, csr_src, dinv, b2, Hf, N_NODES);

    // --- Output ---
    gemm_out_kernel<<<(N_NODES + 31) / 32, dim3(10, 32), 0, stream>>>(
        Hf, Wout, bout, out, N_NODES);
}

// Round 6
// 225.782 us; speedup vs baseline: 1.2393x; 1.0301x over previous
//
#include <hip/hip_runtime.h>
#include <hip/hip_fp16.h>

#define N_NODES 50000
#define N_EDGES 800000
#define F_INN   128
#define F_HID   96
#define F_OUTT  40

typedef _Float16 half8 __attribute__((ext_vector_type(8)));
typedef float    floatx4 __attribute__((ext_vector_type(4)));

// ---------------------------------------------------------------------------
// MFMA GEMM body: T[n][96] (fp16, UNSCALED) = X[n x FI] @ W, via 16x16x32 f16.
// A = W^T tile (m=feature), B = node rows (n=node). 4 waves x 16 nodes = 64/blk.
// TIN = float (load+cvt) or __half (direct half8 load).
// ---------------------------------------------------------------------------
template <int FI, typename TIN>
__device__ __forceinline__ void mfma_gemm_body(
        const TIN* __restrict__ X, const __half* __restrict__ BTg,
        float4* __restrict__ Th4, int n, int bx) {
    __shared__ __half BTl[96 * 136];          // 26112 B
    __shared__ __half OUTl[4 * 16 * 104];     // 13312 B
    int tid = threadIdx.x;
    {   // stage BT (1632 x 16B)
        const int4* s = reinterpret_cast<const int4*>(BTg);
        int4* d = reinterpret_cast<int4*>(BTl);
        for (int i = tid; i < 96 * 136 / 8; i += 256) d[i] = s[i];
    }
    __syncthreads();

    int lane = tid & 63, w = tid >> 6;
    int lm = lane & 15, q = lane >> 4;
    int base = bx * 64 + w * 16;
    int node = base + lm;
    int nclamp = min(node, n - 1);
    const TIN* Xrow = X + (size_t)nclamp * FI;

    floatx4 cf[6];
    #pragma unroll
    for (int t = 0; t < 6; ++t) cf[t] = (floatx4){0.f, 0.f, 0.f, 0.f};

    constexpr int KS = FI / 32;
    #pragma unroll
    for (int ks = 0; ks < KS; ++ks) {
        // B-operand: lane holds k = 32*ks + q*8 .. +7 of this node's row
        half8 bv;
        if constexpr (sizeof(TIN) == 4) {
            const float4* xr = reinterpret_cast<const float4*>(Xrow + 32 * ks + q * 8);
            float4 f0 = xr[0], f1 = xr[1];
            union { half8 v; __half2 h[4]; } b;
            b.h[0] = __floats2half2_rn(f0.x, f0.y);
            b.h[1] = __floats2half2_rn(f0.z, f0.w);
            b.h[2] = __floats2half2_rn(f1.x, f1.y);
            b.h[3] = __floats2half2_rn(f1.z, f1.w);
            bv = b.v;
        } else {
            bv = *reinterpret_cast<const half8*>(Xrow + 32 * ks + q * 8);
        }
        #pragma unroll
        for (int t = 0; t < 6; ++t) {
            half8 a = *reinterpret_cast<const half8*>(
                &BTl[(t * 16 + lm) * 136 + q * 8 + 32 * ks]);
            cf[t] = __builtin_amdgcn_mfma_f32_16x16x32_f16(a, bv, cf[t], 0, 0, 0);
        }
    }

    // Epilogue: D[row=q*4+r][col=lm] = out[feature = t*16+q*4+r][node=lm].
    __half* orow = OUTl + (w * 16 + lm) * 104;
    #pragma unroll
    for (int t = 0; t < 6; ++t) {
        union { int2 i2; __half2 h[2]; } u;
        u.h[0] = __floats2half2_rn(cf[t][0], cf[t][1]);
        u.h[1] = __floats2half2_rn(cf[t][2], cf[t][3]);
        *reinterpret_cast<int2*>(&orow[t * 16 + q * 4]) = u.i2;
    }
    // Same-wave LDS round-trip: coalesced fp16 row store (12 x float4 per node).
    #pragma unroll
    for (int R = 0; R < 3; ++R) {
        int nl = lane >> 2, c = (lane & 3) + 4 * R;
        float4 v = *reinterpret_cast<const float4*>(&OUTl[(w * 16 + nl) * 104 + c * 8]);
        int gn = base + nl;
        if (gn < n) Th4[(size_t)gn * 12 + c] = v;
    }
}

// ---------------------------------------------------------------------------
// Fused: count (blocks [0,nCB)) + gemm L1 (blocks [nCB, nCB+GB)) — independent.
// ---------------------------------------------------------------------------
__global__ __launch_bounds__(256) void count_gemm1_kernel(
        const int* __restrict__ dst, int* __restrict__ counts4, int* __restrict__ rank,
        int e, const float* __restrict__ X, const __half* __restrict__ BT1,
        float4* __restrict__ Th4, int n, int nCB) {
    if ((int)blockIdx.x < nCB) {
        int i = blockIdx.x * 256 + threadIdx.x;
        if (i < e) rank[i] = atomicAdd(&counts4[dst[i] * 4 + (i & 3)], 1);
    } else {
        mfma_gemm_body<F_INN, float>(X, BT1, Th4, n, blockIdx.x - nCB);
    }
}

template <int FI, typename TIN>
__global__ __launch_bounds__(256) void mfma_gemm_kernel(
        const TIN* __restrict__ X, const __half* __restrict__ BTg,
        float4* __restrict__ Th4, int n) {
    mfma_gemm_body<FI, TIN>(X, BTg, Th4, n, blockIdx.x);
}

// ---------------------------------------------------------------------------
// Weight transpose + fp16: W[K x 96] -> BT[96][136] (pad 8). W1 & W2 together.
// ---------------------------------------------------------------------------
__global__ void wt_kernel(const float* __restrict__ W1, const float* __restrict__ W2,
                          __half* __restrict__ BT1, __half* __restrict__ BT2) {
    int i = blockIdx.x * 256 + threadIdx.x;
    if (i < 96 * 128) {
        int j = i / 128, k = i - j * 128;
        BT1[j * 136 + k] = __float2half(W1[k * 96 + j]);
    } else if (i < 96 * 128 + 96 * 96) {
        int t = i - 96 * 128;
        int j = t / 96, k = t - j * 96;
        BT2[j * 136 + k] = __float2half(W2[k * 96 + j]);
    }
}

// ---------------------------------------------------------------------------
// Scan phase 1: per-block exclusive scan of node degrees; dinv; block sums.
// ---------------------------------------------------------------------------
__global__ __launch_bounds__(1024) void scan_local_kernel(
        const int4* __restrict__ counts4, int* __restrict__ row_start,
        float* __restrict__ dinv, int* __restrict__ blk_sums, int n) {
    __shared__ int wave_sums[16];
    int tid = threadIdx.x, lane = tid & 63, wid = tid >> 6;
    int i = blockIdx.x * 1024 + tid;
    int v = 0;
    if (i < n) {
        int4 c = counts4[i];
        v = c.x + c.y + c.z + c.w;
    }
    int val = v;
    #pragma unroll
    for (int off = 1; off < 64; off <<= 1) {
        int u = __shfl_up(val, off, 64);
        if (lane >= off) val += u;
    }
    if (lane == 63) wave_sums[wid] = val;
    __syncthreads();
    if (wid == 0) {
        int w = (lane < 16) ? wave_sums[lane] : 0;
        #pragma unroll
        for (int off = 1; off < 16; off <<= 1) {
            int u = __shfl_up(w, off, 64);
            if (lane >= off) w += u;
        }
        if (lane < 16) wave_sums[lane] = w;
    }
    __syncthreads();
    int excl = ((wid == 0) ? 0 : wave_sums[wid - 1]) + (val - v);
    if (i < n) {
        row_start[i] = excl;                  // local; global offset in phase 2
        dinv[i] = rsqrtf((float)(v + 1));     // +1 self loop
    }
    if (tid == 0) blk_sums[blockIdx.x] = wave_sums[15];
}

// ---------------------------------------------------------------------------
// Scan phase 2+3 fused: every block redundantly scans the <=64 block sums,
// applies its own offset, emits per-shard bases base4. Block 0 writes total.
// ---------------------------------------------------------------------------
__global__ __launch_bounds__(1024) void scan_apply_kernel(
        int* __restrict__ row_start, const int* __restrict__ blk_sums,
        const int4* __restrict__ counts4, int4* __restrict__ base4, int n, int nblk) {
    __shared__ int s_my, s_tot;
    int tid = threadIdx.x;
    if (tid < 64) {
        int v = (tid < nblk) ? blk_sums[tid] : 0;
        int val = v;
        #pragma unroll
        for (int off = 1; off < 64; off <<= 1) {
            int u = __shfl_up(val, off, 64);
            if (tid >= off) val += u;
        }
        if (tid == (int)blockIdx.x) s_my = val - v;   // exclusive prefix
        if (tid == 63) s_tot = val;                   // grand total == E
    }
    __syncthreads();
    int i = blockIdx.x * 1024 + tid;
    if (i < n) {
        int4 c = counts4[i];
        int b = row_start[i] + s_my;
        row_start[i] = b;
        base4[i] = make_int4(b, b + c.x, b + c.x + c.y, b + c.x + c.y + c.z);
    }
    if (blockIdx.x == 0 && tid == 0) row_start[n] = s_tot;
}

// Atomic-free fill: pos = base4[dst].shard + rank.  One scattered 4B store.
__global__ void fill_csr_kernel(const int* __restrict__ src, const int* __restrict__ dst,
                                const int* __restrict__ rank, const int* __restrict__ base4,
                                int* __restrict__ csr_src, int e) {
    int i = blockIdx.x * blockDim.x + threadIdx.x;
    if (i >= e) return;
    csr_src[base4[dst[i] * 4 + (i & 3)] + rank[i]] = src[i];
}

// ---------------------------------------------------------------------------
// Aggregation: one wave per node; T unscaled fp16; per-edge weight dinv[s] is
// a wave-uniform SCALAR load.  H[d] = relu(dinv[d]*(Σ dinv[s]T[s] + dinv[d]T[d]) + b)
// Output fp16.
// ---------------------------------------------------------------------------
__global__ __launch_bounds__(256) void agg_kernel(
        const __half2* __restrict__ T, const int* __restrict__ row_start,
        const int* __restrict__ csr_src, const float* __restrict__ dinv,
        const float* __restrict__ bias, __half2* __restrict__ H, int n) {
    int lane = threadIdx.x & 63;
    int node = __builtin_amdgcn_readfirstlane(blockIdx.x * 4 + (threadIdx.x >> 6));
    if (node >= n) return;
    int fl = min(lane, 47);                    // lanes 48..63 duplicate lane 47

    float dn = dinv[node];
    float2 self = __half22float2(T[(size_t)node * 48 + fl]);
    float accx = dn * self.x, accy = dn * self.y;   // dinv[d]*T[d]

    int idx = row_start[node];
    int end = row_start[node + 1];
    for (; idx + 8 <= end; idx += 8) {
        int s[8];
        #pragma unroll
        for (int u = 0; u < 8; ++u) s[u] = csr_src[idx + u];
        float ws[8];
        #pragma unroll
        for (int u = 0; u < 8; ++u) ws[u] = dinv[s[u]];          // scalar loads
        float2 f[8];
        #pragma unroll
        for (int u = 0; u < 8; ++u) f[u] = __half22float2(T[(size_t)s[u] * 48 + fl]);
        #pragma unroll
        for (int u = 0; u < 8; ++u) {
            accx = fmaf(ws[u], f[u].x, accx);
            accy = fmaf(ws[u], f[u].y, accy);
        }
    }
    for (; idx < end; ++idx) {
        int s = csr_src[idx];
        float w = dinv[s];
        float2 f = __half22float2(T[(size_t)s * 48 + fl]);
        accx = fmaf(w, f.x, accx);
        accy = fmaf(w, f.y, accy);
    }
    if (lane < 48) {
        float2 b = reinterpret_cast<const float2*>(bias)[lane];
        float ox = fmaxf(fmaf(dn, accx, b.x), 0.f);
        float oy = fmaxf(fmaf(dn, accy, b.y), 0.f);
        H[(size_t)node * 48 + lane] = __floats2half2_rn(ox, oy);
    }
}

// ---------------------------------------------------------------------------
// Output GEMM: out[n x 40] = H[n x 96](fp16) @ W[96 x 40] + bias (fp32 acc).
// ---------------------------------------------------------------------------
__global__ __launch_bounds__(320) void gemm_out_kernel(
        const __half2* __restrict__ A, const float* __restrict__ W,
        const float* __restrict__ bias, float* __restrict__ C, int n) {
    __shared__ float Wlds[96 * 40];
    int tid = threadIdx.y * 10 + threadIdx.x;
    for (int i = tid; i < 96 * 10; i += 320)
        reinterpret_cast<float4*>(Wlds)[i] = reinterpret_cast<const float4*>(W)[i];
    __syncthreads();

    int j    = threadIdx.x * 4;
    int node = blockIdx.x * 32 + threadIdx.y;
    int nc   = min(node, n - 1);
    const __half2* Ah = A + (size_t)nc * 48;
    float4 acc = make_float4(0.f, 0.f, 0.f, 0.f);
    for (int k2 = 0; k2 < 48; k2 += 2) {          // k = 2*k2 .. 2*k2+3
        float2 a01 = __half22float2(Ah[k2]);
        float2 a23 = __half22float2(Ah[k2 + 1]);
        int k = 2 * k2;
        float4 w0 = *reinterpret_cast<const float4*>(Wlds + (k + 0) * 40 + j);
        float4 w1 = *reinterpret_cast<const float4*>(Wlds + (k + 1) * 40 + j);
        float4 w2 = *reinterpret_cast<const float4*>(Wlds + (k + 2) * 40 + j);
        float4 w3 = *reinterpret_cast<const float4*>(Wlds + (k + 3) * 40 + j);
        acc.x += a01.x * w0.x + a01.y * w1.x + a23.x * w2.x + a23.y * w3.x;
        acc.y += a01.x * w0.y + a01.y * w1.y + a23.x * w2.y + a23.y * w3.y;
        acc.z += a01.x * w0.z + a01.y * w1.z + a23.x * w2.z + a23.y * w3.z;
        acc.w += a01.x * w0.w + a01.y * w1.w + a23.x * w2.w + a23.y * w3.w;
    }
    if (node < n) {
        float4 b = *reinterpret_cast<const float4*>(bias + j);
        acc.x += b.x; acc.y += b.y; acc.z += b.z; acc.w += b.w;
        *reinterpret_cast<float4*>(C + (size_t)node * 40 + j) = acc;
    }
}

// ---------------------------------------------------------------------------

extern "C" void kernel_launch(void* const* d_in, const int* in_sizes, int n_in,
                              void* d_out, int out_size, void* d_ws, size_t ws_size,
                              hipStream_t stream) {
    const float* x    = (const float*)d_in[0];
    const int*   ei   = (const int*)d_in[1];
    const float* W1   = (const float*)d_in[2];
    const float* b1   = (const float*)d_in[3];
    const float* W2   = (const float*)d_in[4];
    const float* b2   = (const float*)d_in[5];
    const float* Wout = (const float*)d_in[6];
    const float* bout = (const float*)d_in[7];
    float*       out  = (float*)d_out;

    const int* src = ei;            // edge_index[0]
    const int* dst = ei + N_EDGES;  // edge_index[1]

    char* ws = (char*)d_ws;
    size_t off = 0;
    auto alloc = [&](size_t bytes) {
        size_t o = off;
        off = (off + bytes + 511) & ~(size_t)511;
        return (void*)(ws + o);
    };
    int*     counts4   = (int*)    alloc((size_t)N_NODES * 4 * sizeof(int));
    int4*    base4     = (int4*)   alloc((size_t)N_NODES * sizeof(int4));
    int*     row_start = (int*)    alloc((N_NODES + 1) * sizeof(int));
    float*   dinv      = (float*)  alloc(N_NODES * sizeof(float));
    int*     blk_sums  = (int*)    alloc(64 * sizeof(int));
    int*     rank      = (int*)    alloc((size_t)N_EDGES * sizeof(int));
    int*     csr_src   = (int*)    alloc((size_t)N_EDGES * sizeof(int));
    __half*  BT1       = (__half*) alloc((size_t)96 * 136 * sizeof(__half));
    __half*  BT2       = (__half*) alloc((size_t)96 * 136 * sizeof(__half));
    __half2* Th        = (__half2*)alloc((size_t)N_NODES * 48 * sizeof(__half2));
    __half2* Hh        = (__half2*)alloc((size_t)N_NODES * 48 * sizeof(__half2));

    const int NSCAN = (N_NODES + 1023) / 1024;   // 49
    const int CB    = (N_EDGES + 255) / 256;     // 3125 count blocks
    const int GB    = (N_NODES + 63) / 64;       // 782 gemm blocks

    // --- prep ---
    hipMemsetAsync(counts4, 0, (size_t)N_NODES * 4 * sizeof(int), stream);
    wt_kernel<<<(96 * 128 + 96 * 96 + 255) / 256, 256, 0, stream>>>(W1, W2, BT1, BT2);

    // --- fused: edge counting + layer-1 GEMM (independent) ---
    count_gemm1_kernel<<<CB + GB, 256, 0, stream>>>(
        dst, counts4, rank, N_EDGES, x, BT1, (float4*)Th, N_NODES, CB);

    // --- scan (2 launches) + fill ---
    scan_local_kernel<<<NSCAN, 1024, 0, stream>>>(
        (const int4*)counts4, row_start, dinv, blk_sums, N_NODES);
    scan_apply_kernel<<<NSCAN, 1024, 0, stream>>>(
        row_start, blk_sums, (const int4*)counts4, base4, N_NODES, NSCAN);
    fill_csr_kernel<<<CB, 256, 0, stream>>>(
        src, dst, rank, (const int*)base4, csr_src, N_EDGES);

    // --- layer 1 aggregation -> H (fp16) ---
    agg_kernel<<<(N_NODES + 3) / 4, 256, 0, stream>>>(
        Th, row_start, csr_src, dinv, b1, Hh, N_NODES);

    // --- layer 2: GEMM (fp16 in) + aggregation ---
    mfma_gemm_kernel<F_HID, __half><<<GB, 256, 0, stream>>>(
        (const __half*)Hh, BT2, (float4*)Th, N_NODES);
    agg_kernel<<<(N_NODES + 3) / 4, 256, 0, stream>>>(
        Th, row_start, csr_src, dinv, b2, Hh, N_NODES);

    // --- output ---
    gemm_out_kernel<<<(N_NODES + 31) / 32, dim3(10, 32), 0, stream>>>(
        Hh, Wout, bout, out, N_NODES);
}